// Round 5
// baseline (104.825 us; speedup 1.0000x reference)
//
#include <hip/hip_runtime.h>

#define SEQ 1024

typedef __attribute__((ext_vector_type(2))) float f2;

// h storage: row k = two 16B slots s=2k, 2k+1; physical slot P(s)=s^((s>>6)&7)
// (word addr 4*P). Bijective involution (bits 0..2 XORed by untouched bits 6..8).
// Access patterns (bank cluster = 4-bank group = P&7):
//  - inner key read: s = kh*1024 + m*64 + 2i -> cluster ((2i)&7)^(m&7); per
//    wave-read (i,kh fixed) the 16 m-lanes hit all 8 clusters 2x -> 2-way, free.
//  - stage-0 store: 64 consecutive rows/wave -> all 8 clusters 8-deep
//    (bandwidth-optimal 128B/clk).
//  - q-loads: 16-lane broadcast groups, 4 distinct slots/read.
static __device__ __forceinline__ int slot_addr(int s) {
    return (s ^ ((s >> 6) & 7)) << 2;
}

// Closed-form qlayer for one token row y[0..7]:
// angles a = {y0+t0, y1+t1, y2+y3+t2, t3, y4+t4, y5+t5, y6+t6, y7+t7}
// c_w = cos(a_w); out[0] = c1..c7, out[w] = c0..cw (w>=1).
static __device__ __forceinline__ void qrow(const float th[8], const float y[8], float o[8]) {
    float a[8];
    a[0] = y[0] + th[0];
    a[1] = y[1] + th[1];
    a[2] = y[2] + y[3] + th[2];
    a[3] = th[3];
    a[4] = y[4] + th[4];
    a[5] = y[5] + th[5];
    a[6] = y[6] + th[6];
    a[7] = y[7] + th[7];
    float c[8];
#pragma unroll
    for (int w = 0; w < 8; ++w) c[w] = __cosf(a[w]);
    o[1] = c[0] * c[1];
#pragma unroll
    for (int w = 2; w < 8; ++w) o[w] = o[w - 1] * c[w];
    float s = c[7];
#pragma unroll
    for (int w = 6; w >= 1; --w) s *= c[w];
    o[0] = s;
}

// Fused qlayer -> 2-head attention (dk=4) -> qlayer.
// v6 (instruction-diet test; structure IDENTICAL to v5/R4 for clean A/B):
// 512 blocks (16 batches x 32 tiles of 32 q), 512 threads, 42 KB LDS.
// Inner-loop changes only:
//  - query-packed f2 math: d = sum_d {qA_d,qB_d}*{k_d,k_d} -> 8 pk_fma gives
//    BOTH dots, no horizontal add (was: 8 pk + 2 hadd per key).
//  - swizzled addresses hoisted: addr(i) = abase ^ (8i) / abase ^ (8i+4),
//    abase computed once (low-6 bits of sbase are 0, 2i < 64 -> no carry).
//  - full unroll: XOR offsets become immediates, no loop control.
// Per-iter issue ~24 VALU + 4 trans (was ~34 + 4).
__global__ __launch_bounds__(512, 4) void mhaq_fused(const float* __restrict__ x,
                                                     const float* __restrict__ theta,
                                                     float* __restrict__ out) {
    __shared__ __align__(16) float smem[8192 + 2560];
    float* const part = smem + 8192;

    const int b   = blockIdx.x >> 5;         // batch
    const int qof = (blockIdx.x & 31) << 5;  // first query of this block's 32
    const int t   = threadIdx.x;

    float th[8];
#pragma unroll
    for (int w = 0; w < 8; ++w) th[w] = theta[w];

    // ---- Stage 0: h[b] (1024 x 8) into LDS (2 rows/thread) ----
    const float4* xb = (const float4*)(x + (size_t)b * SEQ * 8);
    float4 va[2], vb[2];
#pragma unroll
    for (int r = 0; r < 2; ++r) {
        const int k = t + (r << 9);
        va[r] = xb[2 * k];
        vb[r] = xb[2 * k + 1];
    }
#pragma unroll
    for (int r = 0; r < 2; ++r) {
        const int k = t + (r << 9);
        const float y[8] = {va[r].x, va[r].y, va[r].z, va[r].w,
                            vb[r].x, vb[r].y, vb[r].z, vb[r].w};
        float o[8];
        qrow(th, y, o);
        *(float4*)&smem[slot_addr(2 * k)]     = make_float4(o[0], o[1], o[2], o[3]);
        *(float4*)&smem[slot_addr(2 * k + 1)] = make_float4(o[4], o[5], o[6], o[7]);
    }
    __syncthreads();

    // ---- Stage 2: attention inner loop ----
    const int lane = t & 63;
    const int wv   = t >> 6;      // wave 0..7
    const int qs   = wv >> 1;     // 8-query set 0..3
    const int kh   = wv & 1;      // key half 0..1 (512 keys)
    const int g    = lane >> 4;   // 2-query group 0..3
    const int m    = lane & 15;   // 32-key chunk 0..15
    const int q0   = qof + (qs << 3) + (g << 1);

    const float qscale = 0.5f * 1.44269504f;  // 1/sqrt(dk) * log2(e)
    // query-packed fragments: qp0[d] = {qA_d, qB_d}*s (head0 dims),
    // qp1[d] = {qA_{4+d}, qB_{4+d}}*s (head1 dims).
    const float4 A0 = *(const float4*)&smem[slot_addr(2 * q0)];
    const float4 A1 = *(const float4*)&smem[slot_addr(2 * q0 + 1)];
    const float4 B0 = *(const float4*)&smem[slot_addr(2 * q0 + 2)];
    const float4 B1 = *(const float4*)&smem[slot_addr(2 * q0 + 3)];
    f2 qp0[4], qp1[4];
    qp0[0] = f2{A0.x, B0.x} * qscale;
    qp0[1] = f2{A0.y, B0.y} * qscale;
    qp0[2] = f2{A0.z, B0.z} * qscale;
    qp0[3] = f2{A0.w, B0.w} * qscale;
    qp1[0] = f2{A1.x, B1.x} * qscale;
    qp1[1] = f2{A1.y, B1.y} * qscale;
    qp1[2] = f2{A1.z, B1.z} * qscale;
    qp1[3] = f2{A1.w, B1.w} * qscale;

    // accumulators, per query: l0,l1 + a01,a23 (head0) + a45,a67 (head1)
    float lA0 = 0.f, lA1 = 0.f, lB0 = 0.f, lB1 = 0.f;
    f2 aA01 = {0.f, 0.f}, aA23 = {0.f, 0.f}, aA45 = {0.f, 0.f}, aA67 = {0.f, 0.f};
    f2 aB01 = {0.f, 0.f}, aB23 = {0.f, 0.f}, aB45 = {0.f, 0.f}, aB67 = {0.f, 0.f};

    const int sbase = (kh << 10) + (m << 6);     // slot of this lane's first key
    const int abase = slot_addr(sbase);          // word addr; low 6 bits of sbase = 0
#pragma unroll
    for (int i = 0; i < 32; ++i) {
        // slot sbase+2i   -> word abase ^ (8i)
        // slot sbase+2i+1 -> word abase ^ (8i+4)   (no carries: 2i+1 < 64)
        const float4 k0 = *(const float4*)&smem[abase ^ (i << 3)];
        const float4 k1 = *(const float4*)&smem[abase ^ ((i << 3) | 4)];
        const f2 k01 = {k0.x, k0.y}, k23 = {k0.z, k0.w};
        const f2 k45 = {k1.x, k1.y}, k67 = {k1.z, k1.w};
        // packed dots: d0 = {qA.k, qB.k} head0; d1 = head1
        f2 d0 = qp0[0] * f2{k0.x, k0.x};
        d0 += qp0[1] * f2{k0.y, k0.y};
        d0 += qp0[2] * f2{k0.z, k0.z};
        d0 += qp0[3] * f2{k0.w, k0.w};
        f2 d1 = qp1[0] * f2{k1.x, k1.x};
        d1 += qp1[1] * f2{k1.y, k1.y};
        d1 += qp1[2] * f2{k1.z, k1.z};
        d1 += qp1[3] * f2{k1.w, k1.w};
        const float eA0 = __builtin_amdgcn_exp2f(d0.x);
        const float eB0 = __builtin_amdgcn_exp2f(d0.y);
        const float eA1 = __builtin_amdgcn_exp2f(d1.x);
        const float eB1 = __builtin_amdgcn_exp2f(d1.y);
        lA0 += eA0; lA1 += eA1; lB0 += eB0; lB1 += eB1;
        aA01 += f2{eA0, eA0} * k01;
        aA23 += f2{eA0, eA0} * k23;
        aA45 += f2{eA1, eA1} * k45;
        aA67 += f2{eA1, eA1} * k67;
        aB01 += f2{eB0, eB0} * k01;
        aB23 += f2{eB0, eB0} * k23;
        aB45 += f2{eB1, eB1} * k45;
        aB67 += f2{eB1, eB1} * k67;
    }

    // ---- 2-step shfl_xor over m bits 0..1 (reduces groups of 4 m-lanes) ----
    float buf[20];
    buf[0] = lA0;     buf[1] = lA1;
    buf[2] = aA01.x;  buf[3] = aA01.y;
    buf[4] = aA23.x;  buf[5] = aA23.y;
    buf[6] = aA45.x;  buf[7] = aA45.y;
    buf[8] = aA67.x;  buf[9] = aA67.y;
    buf[10] = lB0;    buf[11] = lB1;
    buf[12] = aB01.x; buf[13] = aB01.y;
    buf[14] = aB23.x; buf[15] = aB23.y;
    buf[16] = aB45.x; buf[17] = aB45.y;
    buf[18] = aB67.x; buf[19] = aB67.y;
#pragma unroll
    for (int j = 0; j < 20; ++j) {
        float v = buf[j];
        v += __shfl_xor(v, 1, 64);
        v += __shfl_xor(v, 2, 64);
        buf[j] = v;
    }

    // ---- dump: survivors m%4==0 -> 16 rows/wave, 128 rows x 20 words ----
    // float4 #ii at word 20*rid+4*ii -> cluster (5*rid+ii)&7; 16 consecutive
    // rid hit all 8 clusters 2x -> 2-way, free.
    if ((m & 3) == 0) {
        const int rid = (wv << 4) + (g << 2) + (m >> 2);
        float4* pp = (float4*)&part[rid * 20];
#pragma unroll
        for (int ii = 0; ii < 5; ++ii) pp[ii] = ((const float4*)buf)[ii];
    }
    __syncthreads();

    // ---- combine + finalize: thread q < 32 owns query qof+q ----
    if (t < 32) {
        const int qs2 = t >> 3, g2 = (t >> 1) & 3, qq = t & 1;
        float r[10];
#pragma unroll
        for (int j = 0; j < 10; ++j) {
            float s = 0.f;
#pragma unroll
            for (int kh2 = 0; kh2 < 2; ++kh2)
#pragma unroll
                for (int mv = 0; mv < 4; ++mv)
                    s += part[((((qs2 << 1) + kh2) << 4) + (g2 << 2) + mv) * 20 + qq * 10 + j];
            r[j] = s;
        }
        const float inv0 = 1.0f / r[0];
        const float inv1 = 1.0f / r[1];
        const float y[8] = {r[2] * inv0, r[3] * inv0, r[4] * inv0, r[5] * inv0,
                            r[6] * inv1, r[7] * inv1, r[8] * inv1, r[9] * inv1};
        float o[8];
        qrow(th, y, o);
        float4* op = (float4*)(out + ((size_t)(b * SEQ + qof + t)) * 8);
        op[0] = make_float4(o[0], o[1], o[2], o[3]);
        op[1] = make_float4(o[4], o[5], o[6], o[7]);
    }
}

extern "C" void kernel_launch(void* const* d_in, const int* in_sizes, int n_in,
                              void* d_out, int out_size, void* d_ws, size_t ws_size,
                              hipStream_t stream) {
    const float* x     = (const float*)d_in[0];
    const float* theta = (const float*)d_in[1];
    float* out         = (float*)d_out;
    mhaq_fused<<<dim3(512), dim3(512), 0, stream>>>(x, theta, out);
}

// Round 6
// 65.494 us; speedup vs baseline: 1.6005x; 1.6005x over previous
//
#include <hip/hip_runtime.h>

#define SEQ 1024

typedef __attribute__((ext_vector_type(2))) float f2;

// h storage: row k = two 16B slots s=2k, 2k+1; physical slot P(s)=s^((s>>6)&7)
// (word addr 4*P). Bijective involution (bits 0..2 XORed by untouched bits 6..8).
// Bank clusters (4-bank groups) = P&7:
//  - inner key read: slot sbase^2i -> cluster (m&7)^(2i&7): 16 m-lanes hit all
//    8 clusters 2x -> 2-way, free (m136). NOTE: do NOT linearize the address
//    sequence (re-index i) -- that collapses clusters to 2 (8-way). The
//    per-iter v_xor is the price of the swizzle; 2 ops/iter.
//  - stage-0 store: 64 consecutive rows/wave -> all clusters busy, BW-optimal.
//  - q-loads: 16-lane broadcast groups, 4 distinct slots/read.
static __device__ __forceinline__ int slot_addr(int s) {
    return (s ^ ((s >> 6) & 7)) << 2;
}

// Closed-form qlayer for one token row y[0..7]:
// angles a = {y0+t0, y1+t1, y2+y3+t2, t3, y4+t4, y5+t5, y6+t6, y7+t7}
// c_w = cos(a_w); out[0] = c1..c7, out[w] = c0..cw (w>=1).
static __device__ __forceinline__ void qrow(const float th[8], const float y[8], float o[8]) {
    float a[8];
    a[0] = y[0] + th[0];
    a[1] = y[1] + th[1];
    a[2] = y[2] + y[3] + th[2];
    a[3] = th[3];
    a[4] = y[4] + th[4];
    a[5] = y[5] + th[5];
    a[6] = y[6] + th[6];
    a[7] = y[7] + th[7];
    float c[8];
#pragma unroll
    for (int w = 0; w < 8; ++w) c[w] = __cosf(a[w]);
    o[1] = c[0] * c[1];
#pragma unroll
    for (int w = 2; w < 8; ++w) o[w] = o[w - 1] * c[w];
    float s = c[7];
#pragma unroll
    for (int w = 6; w >= 1; --w) s *= c[w];
    o[0] = s;
}

// Fused qlayer -> 2-head attention (dk=4) -> qlayer.
// v7 = R0 grid (512 blocks x 256 threads -- best measured) + instruction diet,
// WITHOUT the v6 spill (R5: launch_bounds(512,4) empirically capped VGPR at 64
// -> 180 MB scratch traffic; here (256,4) -> cap 128, live ~100).
// Inner loop: query-packed f2 math -- d = sum_d {qX_d,qY_d}*{k_d,k_d} gives
// both dots with NO horizontal add; packed l-accum; full unroll so XOR
// addresses are literals. 36 VALU + 8 trans per key (R0: ~56 + 8).
// Wave wv: qs 16-query set, kh 512-key half; lane: g = 4-query group,
// m = 32-key chunk. Reduction: 2-step shfl_xor over m bits 0..1, survivors
// m%4==0 dump 40 floats at stride 44 (clusters 3*rid mod 8: 8x2 -> 2-way,
// free), 320-unit collector, 32-thread finalize.
__global__ __launch_bounds__(256, 4) void mhaq_fused(const float* __restrict__ x,
                                                     const float* __restrict__ theta,
                                                     float* __restrict__ out) {
    __shared__ __align__(16) float smem[8192 + 2816 + 320];
    float* const part = smem + 8192;
    float* const res  = part + 2816;

    const int b   = blockIdx.x >> 5;         // batch
    const int qof = (blockIdx.x & 31) << 5;  // first query of this block's 32
    const int t   = threadIdx.x;

    float th[8];
#pragma unroll
    for (int w = 0; w < 8; ++w) th[w] = theta[w];

    // ---- Stage 0: h[b] (1024 x 8) into LDS (4 rows/thread) ----
    const float4* xb = (const float4*)(x + (size_t)b * SEQ * 8);
    float4 v0[4], v1[4];
#pragma unroll
    for (int r = 0; r < 4; ++r) {
        const int k = t + (r << 8);
        v0[r] = xb[2 * k];
        v1[r] = xb[2 * k + 1];
    }
#pragma unroll
    for (int r = 0; r < 4; ++r) {
        const int k = t + (r << 8);
        const float y[8] = {v0[r].x, v0[r].y, v0[r].z, v0[r].w,
                            v1[r].x, v1[r].y, v1[r].z, v1[r].w};
        float o[8];
        qrow(th, y, o);
        *(float4*)&smem[slot_addr(2 * k)]     = make_float4(o[0], o[1], o[2], o[3]);
        *(float4*)&smem[slot_addr(2 * k + 1)] = make_float4(o[4], o[5], o[6], o[7]);
    }
    __syncthreads();

    // ---- Stage 2: attention inner loop ----
    const int lane = t & 63;
    const int wv   = t >> 6;      // wave 0..3
    const int qs   = wv >> 1;     // 16-query set 0/1
    const int kh   = wv & 1;      // key half 0/1 (512 keys)
    const int g    = lane >> 4;   // 4-query group 0..3
    const int m    = lane & 15;   // 32-key chunk 0..15
    const int q0   = qof + (qs << 4) + (g << 2);

    const float qscale = 0.5f * 1.44269504f;  // 1/sqrt(dk) * log2(e)
    float4 qa[4], qb[4];
#pragma unroll
    for (int qq = 0; qq < 4; ++qq) {
        qa[qq] = *(const float4*)&smem[slot_addr(2 * (q0 + qq))];      // broadcast
        qb[qq] = *(const float4*)&smem[slot_addr(2 * (q0 + qq) + 1)];  // broadcast
    }
    // query-packed fragments: pk0[p][d] = {q(2p)_d, q(2p+1)_d}*s (head0),
    // pk1[p][d] = same for dims 4..7 (head1).
    f2 pk0[2][4], pk1[2][4];
#pragma unroll
    for (int p = 0; p < 2; ++p) {
        pk0[p][0] = f2{qa[2 * p].x, qa[2 * p + 1].x} * qscale;
        pk0[p][1] = f2{qa[2 * p].y, qa[2 * p + 1].y} * qscale;
        pk0[p][2] = f2{qa[2 * p].z, qa[2 * p + 1].z} * qscale;
        pk0[p][3] = f2{qa[2 * p].w, qa[2 * p + 1].w} * qscale;
        pk1[p][0] = f2{qb[2 * p].x, qb[2 * p + 1].x} * qscale;
        pk1[p][1] = f2{qb[2 * p].y, qb[2 * p + 1].y} * qscale;
        pk1[p][2] = f2{qb[2 * p].z, qb[2 * p + 1].z} * qscale;
        pk1[p][3] = f2{qb[2 * p].w, qb[2 * p + 1].w} * qscale;
    }

    // accumulators: lp0/lp1[p] = packed {l_{2p}, l_{2p+1}} per head;
    // a01..a67[qq] = attention numerators (head0: 01/23, head1: 45/67).
    f2 lp0[2], lp1[2];
    f2 a01[4], a23[4], a45[4], a67[4];
#pragma unroll
    for (int p = 0; p < 2; ++p) { lp0[p] = f2{0.f, 0.f}; lp1[p] = f2{0.f, 0.f}; }
#pragma unroll
    for (int qq = 0; qq < 4; ++qq) {
        a01[qq] = f2{0.f, 0.f};
        a23[qq] = f2{0.f, 0.f};
        a45[qq] = f2{0.f, 0.f};
        a67[qq] = f2{0.f, 0.f};
    }

    const int sbase = (kh << 10) + (m << 6);  // slot of this lane's first key
    const int abase = slot_addr(sbase);       // word addr; low 6 bits of sbase = 0
#pragma unroll
    for (int i = 0; i < 32; ++i) {
        // slot sbase+2i -> word abase ^ (8i); +1 slot -> ^4 (no carries, 2i+1<64)
        const float4 k0 = *(const float4*)&smem[abase ^ (i << 3)];
        const float4 k1 = *(const float4*)&smem[abase ^ ((i << 3) | 4)];
        const f2 k01 = {k0.x, k0.y}, k23 = {k0.z, k0.w};
        const f2 k45 = {k1.x, k1.y}, k67 = {k1.z, k1.w};
#pragma unroll
        for (int p = 0; p < 2; ++p) {
            f2 d0 = pk0[p][0] * f2{k0.x, k0.x};
            d0 += pk0[p][1] * f2{k0.y, k0.y};
            d0 += pk0[p][2] * f2{k0.z, k0.z};
            d0 += pk0[p][3] * f2{k0.w, k0.w};
            f2 d1 = pk1[p][0] * f2{k1.x, k1.x};
            d1 += pk1[p][1] * f2{k1.y, k1.y};
            d1 += pk1[p][2] * f2{k1.z, k1.z};
            d1 += pk1[p][3] * f2{k1.w, k1.w};
            f2 e0, e1;
            e0.x = __builtin_amdgcn_exp2f(d0.x);
            e0.y = __builtin_amdgcn_exp2f(d0.y);
            e1.x = __builtin_amdgcn_exp2f(d1.x);
            e1.y = __builtin_amdgcn_exp2f(d1.y);
            lp0[p] += e0;
            lp1[p] += e1;
            a01[2 * p]     += f2{e0.x, e0.x} * k01;
            a23[2 * p]     += f2{e0.x, e0.x} * k23;
            a01[2 * p + 1] += f2{e0.y, e0.y} * k01;
            a23[2 * p + 1] += f2{e0.y, e0.y} * k23;
            a45[2 * p]     += f2{e1.x, e1.x} * k45;
            a67[2 * p]     += f2{e1.x, e1.x} * k67;
            a45[2 * p + 1] += f2{e1.y, e1.y} * k45;
            a67[2 * p + 1] += f2{e1.y, e1.y} * k67;
        }
    }

    // ---- 2-step shfl_xor over m bits 0..1 (reduces groups of 4 m-lanes) ----
    float buf[40];
#pragma unroll
    for (int qq = 0; qq < 4; ++qq) {
        const int p = qq >> 1, hi = qq & 1;
        buf[qq * 10 + 0] = hi ? lp0[p].y : lp0[p].x;
        buf[qq * 10 + 1] = hi ? lp1[p].y : lp1[p].x;
        buf[qq * 10 + 2] = a01[qq].x;
        buf[qq * 10 + 3] = a01[qq].y;
        buf[qq * 10 + 4] = a23[qq].x;
        buf[qq * 10 + 5] = a23[qq].y;
        buf[qq * 10 + 6] = a45[qq].x;
        buf[qq * 10 + 7] = a45[qq].y;
        buf[qq * 10 + 8] = a67[qq].x;
        buf[qq * 10 + 9] = a67[qq].y;
    }
#pragma unroll
    for (int j = 0; j < 40; ++j) {
        float v = buf[j];
        v += __shfl_xor(v, 1, 64);
        v += __shfl_xor(v, 2, 64);
        buf[j] = v;
    }

    // ---- dump: survivors m%4==0 -> 16 rows/wave, 64 rows x 44 words ----
    // (part region is separate from h: no barrier needed before the dump)
    if ((m & 3) == 0) {
        const int rid = (wv << 4) + (g << 2) + (m >> 2);
        float4* pp = (float4*)&part[rid * 44];
#pragma unroll
        for (int ii = 0; ii < 10; ++ii) pp[ii] = ((const float4*)buf)[ii];
    }
    __syncthreads();

    // ---- collector: 320 units (32 q x 10 j), each sums 8 contribs ----
    for (int u = t; u < 320; u += 256) {
        const int q  = u / 10;
        const int j  = u - q * 10;
        const int qs2 = q >> 4, g2 = (q >> 2) & 3, qq = q & 3;
        float s = 0.f;
#pragma unroll
        for (int kh2 = 0; kh2 < 2; ++kh2)
#pragma unroll
            for (int mm = 0; mm < 4; ++mm)
                s += part[((((qs2 << 1) + kh2) << 4) + (g2 << 2) + mm) * 44 + qq * 10 + j];
        res[u] = s;
    }
    __syncthreads();

    // ---- epilogue: thread q < 32 finalizes query qof+q ----
    if (t < 32) {
        const float* r = &res[t * 10];
        const float inv0 = 1.0f / r[0];
        const float inv1 = 1.0f / r[1];
        const float y[8] = {r[2] * inv0, r[3] * inv0, r[4] * inv0, r[5] * inv0,
                            r[6] * inv1, r[7] * inv1, r[8] * inv1, r[9] * inv1};
        float o[8];
        qrow(th, y, o);
        float4* op = (float4*)(out + ((size_t)(b * SEQ + qof + t)) * 8);
        op[0] = make_float4(o[0], o[1], o[2], o[3]);
        op[1] = make_float4(o[4], o[5], o[6], o[7]);
    }
}

extern "C" void kernel_launch(void* const* d_in, const int* in_sizes, int n_in,
                              void* d_out, int out_size, void* d_ws, size_t ws_size,
                              hipStream_t stream) {
    const float* x     = (const float*)d_in[0];
    const float* theta = (const float*)d_in[1];
    float* out         = (float*)d_out;
    mhaq_fused<<<dim3(512), dim3(256), 0, stream>>>(x, theta, out);
}

// Round 7
// 64.268 us; speedup vs baseline: 1.6311x; 1.0191x over previous
//
#include <hip/hip_runtime.h>

#define SEQ 1024

typedef __attribute__((ext_vector_type(2))) float f2;

// h storage: row k = two 16B slots s=2k, 2k+1; physical slot P(s)=s^((s>>6)&7)
// (word addr 4*P). Bijective involution (bits 0..2 XORed by untouched bits 6..8).
// Bank clusters (4-bank groups) = P&7:
//  - inner key read: slot sbase^2i -> cluster (m&7)^(2i&7): 16 m-lanes hit all
//    8 clusters 2x -> 2-way, free (m136). Do NOT linearize the address
//    sequence -- that collapses clusters to 2 (8-way). 2 v_xor/iter is the price.
//  - stage-0 store: 64 consecutive rows/wave -> all clusters busy, BW-optimal.
//  - q-loads: 16-lane broadcast groups, 4 distinct slots/read.
static __device__ __forceinline__ int slot_addr(int s) {
    return (s ^ ((s >> 6) & 7)) << 2;
}

// DPP quad-perm butterfly add: v += v[lane ^ 1] (CTRL=0xB1) or v[lane ^ 2]
// (CTRL=0x4E). VALU full-rate -- replaces __shfl_xor's ds_bpermute (LDS pipe,
// ~8 cyc/wave) with a 2-cyc DPP mov. All lanes active at the call sites.
template <int CTRL>
static __device__ __forceinline__ float dpp_xor_add(float v) {
    const int r = __builtin_amdgcn_mov_dpp(__float_as_int(v), CTRL, 0xF, 0xF, true);
    return v + __int_as_float(r);
}

// Closed-form qlayer for one token row y[0..7]:
// angles a = {y0+t0, y1+t1, y2+y3+t2, t3, y4+t4, y5+t5, y6+t6, y7+t7}
// c_w = cos(a_w); out[0] = c1..c7, out[w] = c0..cw (w>=1).
static __device__ __forceinline__ void qrow(const float th[8], const float y[8], float o[8]) {
    float a[8];
    a[0] = y[0] + th[0];
    a[1] = y[1] + th[1];
    a[2] = y[2] + y[3] + th[2];
    a[3] = th[3];
    a[4] = y[4] + th[4];
    a[5] = y[5] + th[5];
    a[6] = y[6] + th[6];
    a[7] = y[7] + th[7];
    float c[8];
#pragma unroll
    for (int w = 0; w < 8; ++w) c[w] = __cosf(a[w]);
    o[1] = c[0] * c[1];
#pragma unroll
    for (int w = 2; w < 8; ++w) o[w] = o[w - 1] * c[w];
    float s = c[7];
#pragma unroll
    for (int w = 6; w >= 1; --w) s *= c[w];
    o[0] = s;
}

// Fused qlayer -> 2-head attention (dk=4) -> qlayer.
// v8 = v7 (best measured inner loop, frozen) + reduction-path diet:
//  - __shfl_xor -> DPP quad-perm adds (80 LDS-pipe bpermutes -> VALU movs);
//    xor over m bits 0..1 == lane bits 0..1 == within-quad permute.
//  - collector merged into epilogue: one fewer barrier, no res round-trip
//    (epilogue thread q sums its 8 partial rows directly from part).
// Grid 512 blocks x 256 threads, launch_bounds(256,4) (VGPR cap 128; R5
// showed (512,4) caps at 64 -> catastrophic spill -- never again).
__global__ __launch_bounds__(256, 4) void mhaq_fused(const float* __restrict__ x,
                                                     const float* __restrict__ theta,
                                                     float* __restrict__ out) {
    __shared__ __align__(16) float smem[8192 + 2816];
    float* const part = smem + 8192;

    const int b   = blockIdx.x >> 5;         // batch
    const int qof = (blockIdx.x & 31) << 5;  // first query of this block's 32
    const int t   = threadIdx.x;

    float th[8];
#pragma unroll
    for (int w = 0; w < 8; ++w) th[w] = theta[w];

    // ---- Stage 0: h[b] (1024 x 8) into LDS (4 rows/thread) ----
    const float4* xb = (const float4*)(x + (size_t)b * SEQ * 8);
    float4 v0[4], v1[4];
#pragma unroll
    for (int r = 0; r < 4; ++r) {
        const int k = t + (r << 8);
        v0[r] = xb[2 * k];
        v1[r] = xb[2 * k + 1];
    }
#pragma unroll
    for (int r = 0; r < 4; ++r) {
        const int k = t + (r << 8);
        const float y[8] = {v0[r].x, v0[r].y, v0[r].z, v0[r].w,
                            v1[r].x, v1[r].y, v1[r].z, v1[r].w};
        float o[8];
        qrow(th, y, o);
        *(float4*)&smem[slot_addr(2 * k)]     = make_float4(o[0], o[1], o[2], o[3]);
        *(float4*)&smem[slot_addr(2 * k + 1)] = make_float4(o[4], o[5], o[6], o[7]);
    }
    __syncthreads();

    // ---- Stage 2: attention inner loop (identical to v7/R6) ----
    const int lane = t & 63;
    const int wv   = t >> 6;      // wave 0..3
    const int qs   = wv >> 1;     // 16-query set 0/1
    const int kh   = wv & 1;      // key half 0/1 (512 keys)
    const int g    = lane >> 4;   // 4-query group 0..3
    const int m    = lane & 15;   // 32-key chunk 0..15
    const int q0   = qof + (qs << 4) + (g << 2);

    const float qscale = 0.5f * 1.44269504f;  // 1/sqrt(dk) * log2(e)
    float4 qa[4], qb[4];
#pragma unroll
    for (int qq = 0; qq < 4; ++qq) {
        qa[qq] = *(const float4*)&smem[slot_addr(2 * (q0 + qq))];      // broadcast
        qb[qq] = *(const float4*)&smem[slot_addr(2 * (q0 + qq) + 1)];  // broadcast
    }
    // query-packed fragments: pk0[p][d] = {q(2p)_d, q(2p+1)_d}*s (head0),
    // pk1[p][d] = same for dims 4..7 (head1).
    f2 pk0[2][4], pk1[2][4];
#pragma unroll
    for (int p = 0; p < 2; ++p) {
        pk0[p][0] = f2{qa[2 * p].x, qa[2 * p + 1].x} * qscale;
        pk0[p][1] = f2{qa[2 * p].y, qa[2 * p + 1].y} * qscale;
        pk0[p][2] = f2{qa[2 * p].z, qa[2 * p + 1].z} * qscale;
        pk0[p][3] = f2{qa[2 * p].w, qa[2 * p + 1].w} * qscale;
        pk1[p][0] = f2{qb[2 * p].x, qb[2 * p + 1].x} * qscale;
        pk1[p][1] = f2{qb[2 * p].y, qb[2 * p + 1].y} * qscale;
        pk1[p][2] = f2{qb[2 * p].z, qb[2 * p + 1].z} * qscale;
        pk1[p][3] = f2{qb[2 * p].w, qb[2 * p + 1].w} * qscale;
    }

    // accumulators: lp0/lp1[p] = packed {l_{2p}, l_{2p+1}} per head;
    // a01..a67[qq] = attention numerators (head0: 01/23, head1: 45/67).
    f2 lp0[2], lp1[2];
    f2 a01[4], a23[4], a45[4], a67[4];
#pragma unroll
    for (int p = 0; p < 2; ++p) { lp0[p] = f2{0.f, 0.f}; lp1[p] = f2{0.f, 0.f}; }
#pragma unroll
    for (int qq = 0; qq < 4; ++qq) {
        a01[qq] = f2{0.f, 0.f};
        a23[qq] = f2{0.f, 0.f};
        a45[qq] = f2{0.f, 0.f};
        a67[qq] = f2{0.f, 0.f};
    }

    const int sbase = (kh << 10) + (m << 6);  // slot of this lane's first key
    const int abase = slot_addr(sbase);       // word addr; low 6 bits of sbase = 0
#pragma unroll
    for (int i = 0; i < 32; ++i) {
        // slot sbase+2i -> word abase ^ (8i); +1 slot -> ^4 (no carries, 2i+1<64)
        const float4 k0 = *(const float4*)&smem[abase ^ (i << 3)];
        const float4 k1 = *(const float4*)&smem[abase ^ ((i << 3) | 4)];
        const f2 k01 = {k0.x, k0.y}, k23 = {k0.z, k0.w};
        const f2 k45 = {k1.x, k1.y}, k67 = {k1.z, k1.w};
#pragma unroll
        for (int p = 0; p < 2; ++p) {
            f2 d0 = pk0[p][0] * f2{k0.x, k0.x};
            d0 += pk0[p][1] * f2{k0.y, k0.y};
            d0 += pk0[p][2] * f2{k0.z, k0.z};
            d0 += pk0[p][3] * f2{k0.w, k0.w};
            f2 d1 = pk1[p][0] * f2{k1.x, k1.x};
            d1 += pk1[p][1] * f2{k1.y, k1.y};
            d1 += pk1[p][2] * f2{k1.z, k1.z};
            d1 += pk1[p][3] * f2{k1.w, k1.w};
            f2 e0, e1;
            e0.x = __builtin_amdgcn_exp2f(d0.x);
            e0.y = __builtin_amdgcn_exp2f(d0.y);
            e1.x = __builtin_amdgcn_exp2f(d1.x);
            e1.y = __builtin_amdgcn_exp2f(d1.y);
            lp0[p] += e0;
            lp1[p] += e1;
            a01[2 * p]     += f2{e0.x, e0.x} * k01;
            a23[2 * p]     += f2{e0.x, e0.x} * k23;
            a01[2 * p + 1] += f2{e0.y, e0.y} * k01;
            a23[2 * p + 1] += f2{e0.y, e0.y} * k23;
            a45[2 * p]     += f2{e1.x, e1.x} * k45;
            a67[2 * p]     += f2{e1.x, e1.x} * k67;
            a45[2 * p + 1] += f2{e1.y, e1.y} * k45;
            a67[2 * p + 1] += f2{e1.y, e1.y} * k67;
        }
    }

    // ---- 2-step DPP quad-perm reduction over m bits 0..1 (VALU, not LDS) ----
    float buf[40];
#pragma unroll
    for (int qq = 0; qq < 4; ++qq) {
        const int p = qq >> 1, hi = qq & 1;
        buf[qq * 10 + 0] = hi ? lp0[p].y : lp0[p].x;
        buf[qq * 10 + 1] = hi ? lp1[p].y : lp1[p].x;
        buf[qq * 10 + 2] = a01[qq].x;
        buf[qq * 10 + 3] = a01[qq].y;
        buf[qq * 10 + 4] = a23[qq].x;
        buf[qq * 10 + 5] = a23[qq].y;
        buf[qq * 10 + 6] = a45[qq].x;
        buf[qq * 10 + 7] = a45[qq].y;
        buf[qq * 10 + 8] = a67[qq].x;
        buf[qq * 10 + 9] = a67[qq].y;
    }
#pragma unroll
    for (int j = 0; j < 40; ++j)
        buf[j] = dpp_xor_add<0x4E>(dpp_xor_add<0xB1>(buf[j]));

    // ---- dump: survivors m%4==0 -> 16 rows/wave, 64 rows x 44 words ----
    // float4 #ii at word 44*rid+4*ii -> cluster (3*rid+ii)&7; consecutive rid
    // cycle all clusters -> 2-way, free. (part separate from h: no pre-barrier.)
    if ((m & 3) == 0) {
        const int rid = (wv << 4) + (g << 2) + (m >> 2);
        float4* pp = (float4*)&part[rid * 44];
#pragma unroll
        for (int ii = 0; ii < 10; ++ii) pp[ii] = ((const float4*)buf)[ii];
    }
    __syncthreads();

    // ---- epilogue (collector merged): thread q < 32 sums its 8 partial
    // rows directly and finalizes query qof+q. 80 independent LDS reads,
    // pipelined; saves the old collector barrier + res round-trip. ----
    if (t < 32) {
        const int qs2 = t >> 4, g2 = (t >> 2) & 3, qq = t & 3;
        float r[10];
#pragma unroll
        for (int j = 0; j < 10; ++j) r[j] = 0.f;
#pragma unroll
        for (int kh2 = 0; kh2 < 2; ++kh2)
#pragma unroll
            for (int mm = 0; mm < 4; ++mm) {
                const int base = ((((qs2 << 1) + kh2) << 4) + (g2 << 2) + mm) * 44 + qq * 10;
#pragma unroll
                for (int j = 0; j < 10; ++j) r[j] += part[base + j];
            }
        const float inv0 = 1.0f / r[0];
        const float inv1 = 1.0f / r[1];
        const float y[8] = {r[2] * inv0, r[3] * inv0, r[4] * inv0, r[5] * inv0,
                            r[6] * inv1, r[7] * inv1, r[8] * inv1, r[9] * inv1};
        float o[8];
        qrow(th, y, o);
        float4* op = (float4*)(out + ((size_t)(b * SEQ + qof + t)) * 8);
        op[0] = make_float4(o[0], o[1], o[2], o[3]);
        op[1] = make_float4(o[4], o[5], o[6], o[7]);
    }
}

extern "C" void kernel_launch(void* const* d_in, const int* in_sizes, int n_in,
                              void* d_out, int out_size, void* d_ws, size_t ws_size,
                              hipStream_t stream) {
    const float* x     = (const float*)d_in[0];
    const float* theta = (const float*)d_in[1];
    float* out         = (float*)d_out;
    mhaq_fused<<<dim3(512), dim3(256), 0, stream>>>(x, theta, out);
}